// Round 1
// baseline (659.260 us; speedup 1.0000x reference)
//
#include <hip/hip_runtime.h>
#include <hip/hip_bf16.h>

#define N_IN 200000
#define N_OUT 200000
#define K_VOL 27
#define M_PAIRS 100000
#define C_IN 64
#define C_OUT 64

#define MTILE 64
#define LDS_PAD 72   // 64 + 8 bf16 -> 144B row stride, breaks 32-bank aliasing, keeps 16B align

typedef __attribute__((ext_vector_type(4))) float floatx4;
typedef __attribute__((ext_vector_type(8))) short shortx8;

static __device__ __forceinline__ ushort f32_to_bf16(float f) {
    union { float f; unsigned int u; } x; x.f = f;
    unsigned int u = x.u;
    u += 0x7FFFu + ((u >> 16) & 1u);   // round-to-nearest-even
    return (ushort)(u >> 16);
}

// fp32 -> bf16, 4 elements per thread
__global__ void cvt_feats_kernel(const float* __restrict__ src, ushort* __restrict__ dst, int n4) {
    int i = blockIdx.x * blockDim.x + threadIdx.x;
    if (i >= n4) return;
    float4 v = ((const float4*)src)[i];
    ushort4 o;
    o.x = f32_to_bf16(v.x); o.y = f32_to_bf16(v.y);
    o.z = f32_to_bf16(v.z); o.w = f32_to_bf16(v.w);
    ((ushort4*)dst)[i] = o;
}

// kernel[k][c][o] fp32 -> wt[k][o][c] bf16 (transposed so MFMA B-frags are contiguous)
__global__ void cvt_wt_kernel(const float* __restrict__ w, ushort* __restrict__ wt) {
    int idx = blockIdx.x * blockDim.x + threadIdx.x;
    if (idx >= K_VOL * C_IN * C_OUT) return;
    int k   = idx >> 12;          // / 4096
    int rem = idx & 4095;
    int c   = rem >> 6;
    int o   = rem & 63;
    wt[(k << 12) + (o << 6) + c] = f32_to_bf16(w[idx]);
}

// out[n][c] = bias[c]
__global__ void init_bias_kernel(const float* __restrict__ bias, float* __restrict__ out, int n4) {
    int i = blockIdx.x * blockDim.x + threadIdx.x;
    if (i >= n4) return;
    int c = (i * 4) & 63;
    float4 b = *(const float4*)(bias + c);
    ((float4*)out)[i] = b;
}

// gather -> 64x64x64 bf16 MFMA GEMM -> scatter-add (fp32 atomics)
__launch_bounds__(256, 4)
__global__ void spconv_kernel(const ushort* __restrict__ feats,  // [N_IN][64] bf16
                              const ushort* __restrict__ wt,     // [K][64 o][64 c] bf16
                              const int* __restrict__ imap,
                              const int* __restrict__ omap,
                              float* __restrict__ out) {
    __shared__ ushort Asm[MTILE * LDS_PAD];
    __shared__ ushort Wsm[C_OUT * LDS_PAD];
    __shared__ int omap_s[MTILE];

    const int k   = blockIdx.y;
    const int m0  = blockIdx.x * MTILE;
    const int tid = threadIdx.x;
    const int kM  = k * M_PAIRS;

    // stage W_t[k] : 64 rows (o) x 64 (c) bf16, 16B chunks
    #pragma unroll
    for (int p = 0; p < 2; ++p) {
        int cid = tid + p * 256;
        int row = cid >> 3;
        int ch  = cid & 7;
        *(shortx8*)&Wsm[row * LDS_PAD + ch * 8] =
            *(const shortx8*)&wt[(k << 12) + row * 64 + ch * 8];
    }
    // gather A tile: 64 pair-rows x 64 (c) bf16
    #pragma unroll
    for (int p = 0; p < 2; ++p) {
        int cid = tid + p * 256;
        int row = cid >> 3;
        int ch  = cid & 7;
        int m   = m0 + row;
        shortx8 v = {0, 0, 0, 0, 0, 0, 0, 0};
        if (m < M_PAIRS) {
            int g = imap[kM + m];
            v = *(const shortx8*)&feats[(g << 6) + ch * 8];
        }
        *(shortx8*)&Asm[row * LDS_PAD + ch * 8] = v;
    }
    if (tid < MTILE) {
        int m = m0 + tid;
        omap_s[tid] = (m < M_PAIRS) ? omap[kM + m] : -1;
    }
    __syncthreads();

    const int wave = tid >> 6;
    const int lane = tid & 63;
    const int quad = lane >> 4;
    const int l16  = lane & 15;
    const int rbase = wave * 16;

    // A fragments: A[m = l16][k = quad*8 + j (+32)]
    const shortx8 a0 = *(const shortx8*)&Asm[(rbase + l16) * LDS_PAD + quad * 8];
    const shortx8 a1 = *(const shortx8*)&Asm[(rbase + l16) * LDS_PAD + 32 + quad * 8];

    #pragma unroll
    for (int ct = 0; ct < 4; ++ct) {
        // B fragments: B[k = quad*8 + j (+32)][n = l16]  (wt stored [o][c])
        const shortx8 b0 = *(const shortx8*)&Wsm[(ct * 16 + l16) * LDS_PAD + quad * 8];
        const shortx8 b1 = *(const shortx8*)&Wsm[(ct * 16 + l16) * LDS_PAD + 32 + quad * 8];
        floatx4 acc = {0.f, 0.f, 0.f, 0.f};
        acc = __builtin_amdgcn_mfma_f32_16x16x32_bf16(a0, b0, acc, 0, 0, 0);
        acc = __builtin_amdgcn_mfma_f32_16x16x32_bf16(a1, b1, acc, 0, 0, 0);

        const int col = ct * 16 + l16;
        #pragma unroll
        for (int r = 0; r < 4; ++r) {
            int rl = rbase + quad * 4 + r;     // C row = quad*4 + reg
            int orow = omap_s[rl];
            if (orow >= 0) atomicAdd(&out[(orow << 6) + col], acc[r]);
        }
    }
}

extern "C" void kernel_launch(void* const* d_in, const int* in_sizes, int n_in,
                              void* d_out, int out_size, void* d_ws, size_t ws_size,
                              hipStream_t stream) {
    const float* in_feats = (const float*)d_in[0];
    const float* kernelw  = (const float*)d_in[1];
    const float* bias     = (const float*)d_in[2];
    const int*   imap     = (const int*)d_in[3];
    const int*   omap     = (const int*)d_in[4];
    float* out = (float*)d_out;

    ushort* feats_bf = (ushort*)d_ws;                                   // 25,600,000 B
    ushort* wt_bf    = (ushort*)((char*)d_ws + (size_t)N_IN * C_IN * 2); // +221,184 B

    int n4 = N_IN * C_IN / 4;
    cvt_feats_kernel<<<(n4 + 255) / 256, 256, 0, stream>>>(in_feats, feats_bf, n4);
    cvt_wt_kernel<<<(K_VOL * C_IN * C_OUT + 255) / 256, 256, 0, stream>>>(kernelw, wt_bf);
    int o4 = N_OUT * C_OUT / 4;
    init_bias_kernel<<<(o4 + 255) / 256, 256, 0, stream>>>(bias, out, o4);

    dim3 grid((M_PAIRS + MTILE - 1) / MTILE, K_VOL);
    spconv_kernel<<<grid, 256, 0, stream>>>(feats_bf, wt_bf, imap, omap, out);
}